// Round 7
// baseline (2249.285 us; speedup 1.0000x reference)
//
#include <hip/hip_runtime.h>
#include <hip/hip_bf16.h>
#include <stdint.h>

// Problem dims
#define BB 64     // batch
#define SS 512    // seq len
#define HH 512    // hidden
#define DD 300    // embed dim
#define DP 320    // embed dim padded to K%32==0

typedef __attribute__((ext_vector_type(8))) short short8;  // 8 x bf16
typedef __attribute__((ext_vector_type(4))) float f32x4;

__device__ __forceinline__ unsigned short f2bf(float f) {
  unsigned u = __builtin_bit_cast(unsigned, f);
  u += 0x7fffu + ((u >> 16) & 1u);       // RNE
  return (unsigned short)(u >> 16);
}
__device__ __forceinline__ float sigm(float x) { return 1.f / (1.f + __expf(-x)); }
__device__ __forceinline__ float tanh_f(float x) {
  float t = __expf(-2.f * fabsf(x));
  float r = (1.f - t) / (1.f + t);
  return x < 0.f ? -r : r;
}

// Coalesced 16B loads (lane l reads base + l*16). sc1 -> agent-scope (MALL-coherent).
// Results are NOT valid until an explicit s_waitcnt vmcnt(0)!
__device__ __forceinline__ short8 load_frag_sc1(const unsigned short* p) {
  short8 r;
  asm volatile("global_load_dwordx4 %0, %1, off sc1" : "=v"(r) : "v"(p));
  return r;
}
__device__ __forceinline__ short8 load_frag(const unsigned short* p) {
  short8 r;
  asm volatile("global_load_dwordx4 %0, %1, off" : "=v"(r) : "v"(p));
  return r;
}

// ---------------- workspace layout (bytes) ----------------
// A-side frag-ready layouts: element (b, c) of a [64 x 32*NKB] bf16 panel at
// 2B-unit addr: (c>>5)*2048 + (b>>4)*512 + ((c>>3)&3)*128 + (b&15)*8 + (c&7)
// so MFMA A-frag (mtile m, kblk) = base + kblk*2048 + m*512 + lane*8, 16B/lane.
// W is now stored frag-LINEAR per block (see prep_weights) so the one-time
// global->LDS fill is a straight coalesced copy.
#define OFF_ARR   0u          // 16 arrival counters, 512B spaced -> 8192
#define OFF_EP    8192u       // epoch broadcast word; region reserved to 16384
#define OFF_H1    16384u      // h1 ring [2][64KB frag-layout] -> 131072
#define OFF_H2    147456u     // h2 ring [2][64KB frag-layout] -> 131072
#define OFF_C2    278528u     // c2 [64][512] f32 -> 131072
#define OFF_XE    409600u     // xe frag-layout [512][10 kblk][4KB] -> 20971520
#define OFF_W0    21381120u   // Wp0 frag-linear [64 blk][52 frag][512 u16] -> 3407872
#define OFF_W1    24788992u   // Wp1 frag-linear [64 blk][64 frag][512 u16] -> 4194304
#define OFF_B0    28983296u   // bias0p [2048] f32
#define OFF_B1    28991488u   // bias1p [2048] f32
#define MEMSET_BYTES 278528u  // counters + epoch + both h rings

// ---------------- weight prep ----------------
// Gate-row mapping (unchanged): grow = lblk*32 + l32, gate = l32>>3 (i,f,g,o),
// orig = gate*512 + lblk*8 + (l32&7).
// Row content: L0 = [W_hh0 | W_ih0 | pad] (A = [h1_prev | x_t]),
//              L1 = [W_ih1 | W_hh1]       (A = [h1_t | h2_prev]).
// NEW dst layout (frag-linear): block lblk, frag f = nt*NKT + kb (nt = l32>>4,
// kb = k1>>5), within frag: lane = ((k1>>3)&3)*16 + (l32&15), elem = k1&7.
// u16 addr = lblk*(2*NKT*512) + f*512 + lane*8 + elem.  (B-frag of 16x16x32:
// col = lane&15 = gate row, k = (lane>>4)*8 + elem.)
__global__ void prep_weights(const float* __restrict__ Wih0, const float* __restrict__ Whh0,
                             const float* __restrict__ bih0, const float* __restrict__ bhh0,
                             const float* __restrict__ Wih1, const float* __restrict__ Whh1,
                             const float* __restrict__ bih1, const float* __restrict__ bhh1,
                             unsigned short* __restrict__ Wp0, unsigned short* __restrict__ Wp1,
                             float* __restrict__ b0p, float* __restrict__ b1p)
{
  int idx = blockIdx.x * 256 + threadIdx.x;   // over 2048*1024
  int grow = idx >> 10;
  int k1 = idx & 1023;
  int l32 = grow & 31;
  int lblk = grow >> 5;
  int gate = l32 >> 3;
  int orig = gate * 512 + lblk * 8 + (l32 & 7);

  const int nt   = l32 >> 4;
  const int lrow = l32 & 15;
  const int kb   = k1 >> 5;
  const int lane = (((k1 >> 3) & 3) << 4) | lrow;
  const int e    = k1 & 7;

  float v1 = (k1 < 512) ? Wih1[orig * 512 + k1] : Whh1[orig * 512 + (k1 - 512)];
  size_t d1 = (size_t)lblk * 32768 + (size_t)(nt * 32 + kb) * 512 + lane * 8 + e;
  Wp1[d1] = f2bf(v1);

  if (k1 < 832) {
    float v0;
    if (k1 < 512)      v0 = Whh0[orig * 512 + k1];
    else if (k1 < 812) v0 = Wih0[orig * 300 + (k1 - 512)];
    else               v0 = 0.f;
    size_t d0 = (size_t)lblk * 26624 + (size_t)(nt * 26 + kb) * 512 + lane * 8 + e;
    Wp0[d0] = f2bf(v0);
  }
  if (k1 == 0) {
    b0p[grow] = bih0[orig] + bhh0[orig];
    b1p[grow] = bih1[orig] + bhh1[orig];
  }
}

// ---------------- embedding gather -> frag-ready layout ----------------
__global__ void gather_xe(const int* __restrict__ x, const float* __restrict__ emb,
                          unsigned short* __restrict__ xe)
{
  int idx = blockIdx.x * 256 + threadIdx.x;   // SS*BB*DP = 10485760
  int dk = idx % DP;
  int rem = idx / DP;
  int b = rem % BB;
  int t = rem / BB;
  int tok = x[b * SS + t];
  float v = (dk < DD) ? emb[(size_t)tok * DD + dk] : 0.f;
  size_t ua = (size_t)t * 20480 + (size_t)(dk >> 5) * 2048 + (size_t)(b >> 4) * 512
            + (size_t)((dk >> 3) & 3) * 128 + (size_t)(b & 15) * 8 + (dk & 7);
  xe[ua] = f2bf(v);
}

// ---------------- persistent pipelined 2-layer scan ----------------
// 128 blocks x 512 thr; blk<64 -> L0, else L1. Iter k: L0 step t=k (k<512),
// L1 step t=k-1 (k>=1). Barrier: 16 arrival counters (blk>>3, 8 contenders);
// master blk0/wave0 aggregates -> epoch word; workers poll the epoch line.
// W lives in LDS (loaded once, structural residency -- no register-allocator
// fight; rounds 4-6 never got W resident in VGPRs). B-frags are ds_read_b128
// chunks interleaved with MFMA. h exchange: frag-ready coalesced dwordx4 sc1.
template<bool IS_L0>
__device__ __forceinline__ void scan_body(
    int blk,
    const unsigned short* __restrict__ xe,
    const unsigned short* __restrict__ Wp,
    const float* __restrict__ biasP,
    unsigned short* __restrict__ h1r,
    unsigned short* __restrict__ h2r,
    float* __restrict__ c2,
    unsigned int* cnt,
    unsigned short (&w_lds)[32768], float (&gl)[2][64][36], float (&bias_sm)[32])
{
  constexpr int NKT = IS_L0 ? 26 : 32;     // total kblks
  constexpr int NK  = NKT / 2;             // kblks per khalf (13 / 16)

  const int tid  = threadIdx.x;
  const int lane = tid & 63;
  const int wave = tid >> 6;
  const int lrow = lane & 15;
  const int m    = wave & 3;
  const int q    = wave >> 2;
  const int lblk = IS_L0 ? blk : blk - 64;
  const int qkb  = q * NK;                 // first global kblk of this wave

  unsigned int* ep = cnt + 2048;           // epoch word at byte 8192

  if (tid < 32) bias_sm[tid] = biasP[lblk * 32 + tid];

  // ---- one-time W fill: frag-linear global -> LDS, fully coalesced ----
  {
    const short8* src = (const short8*)(Wp + (size_t)lblk * (2 * NKT * 512));
    short8* dst = (short8*)w_lds;
    #pragma unroll 2
    for (int i = tid; i < NKT * 128; i += 512) dst[i] = src[i];
  }
  __syncthreads();

  float creg = 0.f;                 // cell state: 1 cell per thread
  const int pb = tid >> 3;          // pointwise batch
  const int ph = tid & 7;           // pointwise h-offset
  // pointwise h-store unit address (frag layout), constant part:
  const size_t hst = (size_t)(lblk >> 2) * 2048 + (size_t)(pb >> 4) * 512
                   + (size_t)(lblk & 3) * 128 + (size_t)(pb & 15) * 8 + ph;

  for (int k = 0;; ++k) {
    const bool active = IS_L0 ? (k < 512) : (k >= 1);
    short8 a[NK];

    // ---- prefetch cacheable xe fragments (L0 only) before the wait ----
    if (IS_L0 && active) {
      const unsigned short* xet = xe + (size_t)k * 20480;
      #pragma unroll
      for (int j = 0; j < NK; ++j) {
        const int kg = qkb + j;
        if (kg >= 16)
          a[j] = load_frag(xet + (size_t)(kg - 16) * 2048 + (size_t)m * 512 + lane * 8);
      }
    }

    // ---- barrier wait: iteration k-1 complete everywhere (master + epoch) ----
    if (k >= 1) {
      if (blk == 0) {
        if (wave == 0) {
          const unsigned tgt = (unsigned)k * 8u;
          int guard = 0;
          for (;;) {
            unsigned v = (lane < 16)
                ? __hip_atomic_load(cnt + lane * 128, __ATOMIC_RELAXED, __HIP_MEMORY_SCOPE_AGENT)
                : tgt;
            if (__all(v >= tgt)) break;
            if (++guard > (1 << 18)) break;
            __builtin_amdgcn_s_sleep(1);
          }
          if (lane == 0)
            __hip_atomic_store(ep, (unsigned)k, __ATOMIC_RELAXED, __HIP_MEMORY_SCOPE_AGENT);
        }
      } else {
        if (wave == 0) {
          int guard = 0;
          for (;;) {
            unsigned v = __hip_atomic_load(ep, __ATOMIC_RELAXED, __HIP_MEMORY_SCOPE_AGENT);
            if (v >= (unsigned)k) break;
            if (++guard > (1 << 18)) break;
            __builtin_amdgcn_s_sleep(2);
          }
        }
      }
      __syncthreads();
    }

    if (active) {
      const int t = IS_L0 ? k : k - 1;
      const unsigned short* hA = h1r + (size_t)((IS_L0 ? (t + 1) : t) & 1) * 32768;
      const unsigned short* hB = h2r + (size_t)((t + 1) & 1) * 32768;

      // ---- h fragment loads (coalesced sc1, issued immediately post-barrier) ----
      #pragma unroll
      for (int j = 0; j < NK; ++j) {
        const int kg = qkb + j;
        if (kg < 16) {
          a[j] = load_frag_sc1(hA + (size_t)kg * 2048 + (size_t)m * 512 + lane * 8);
        } else if (!IS_L0) {
          a[j] = load_frag_sc1(hB + (size_t)(kg - 16) * 2048 + (size_t)m * 512 + lane * 8);
        }
      }
      asm volatile("s_waitcnt vmcnt(0)" ::: "memory");
      __builtin_amdgcn_sched_barrier(0);

      // ---- MFMA, B-frags streamed from LDS (compiler lgkm-pipelines) ----
      f32x4 acc0 = {0.f, 0.f, 0.f, 0.f};
      f32x4 acc1 = {0.f, 0.f, 0.f, 0.f};
      const unsigned short* wl = w_lds + lane * 8;
      #pragma unroll
      for (int j = 0; j < NK; ++j) {
        const int kg = qkb + j;
        short8 b0 = *(const short8*)(wl + (size_t)kg * 512);
        short8 b1 = *(const short8*)(wl + (size_t)(NKT + kg) * 512);
        acc0 = __builtin_amdgcn_mfma_f32_16x16x32_bf16(a[j], b0, acc0, 0, 0, 0);
        acc1 = __builtin_amdgcn_mfma_f32_16x16x32_bf16(a[j], b1, acc1, 0, 0, 0);
      }
      #pragma unroll
      for (int r = 0; r < 4; ++r) {
        const int bb = m * 16 + (lane >> 4) * 4 + r;
        gl[q][bb][lrow]      = acc0[r];
        gl[q][bb][16 + lrow] = acc1[r];
      }
      __syncthreads();

      // ---- pointwise gates + frag-layout h store (contiguous per wave) ----
      {
        float gi = gl[0][pb][ph]      + gl[1][pb][ph]      + bias_sm[ph];
        float gf = gl[0][pb][8 + ph]  + gl[1][pb][8 + ph]  + bias_sm[8 + ph];
        float gg = gl[0][pb][16 + ph] + gl[1][pb][16 + ph] + bias_sm[16 + ph];
        float go = gl[0][pb][24 + ph] + gl[1][pb][24 + ph] + bias_sm[24 + ph];
        float iv = sigm(gi), fv = sigm(gf), ov = sigm(go), gv = tanh_f(gg);
        creg = fv * creg + iv * gv;
        float hv = ov * tanh_f(creg);
        unsigned short hb = f2bf(hv);
        unsigned pair = (unsigned)hb | ((unsigned)(unsigned short)__shfl_down((int)hb, 1) << 16);
        unsigned short* hw = (IS_L0 ? h1r : h2r) + (size_t)(t & 1) * 32768 + hst;
        if ((ph & 1) == 0)
          __hip_atomic_store((unsigned*)hw, pair, __ATOMIC_RELAXED, __HIP_MEMORY_SCOPE_AGENT);
        if (!IS_L0 && k == 512) c2[pb * HH + lblk * 8 + ph] = creg;
      }
      // drain h stores to the coherence point before signaling
      asm volatile("s_waitcnt vmcnt(0)" ::: "memory");
    }

    if (k == 512) break;
    // ---- signal iteration-k completion (8 contenders per counter) ----
    __syncthreads();
    if (tid == 0)
      __hip_atomic_fetch_add(cnt + (blk >> 3) * 128, 1u, __ATOMIC_RELAXED,
                             __HIP_MEMORY_SCOPE_AGENT);
  }
}

__global__ void __launch_bounds__(512, 1)
lstm_scan(const unsigned short* __restrict__ xe,
          const unsigned short* __restrict__ Wp0,
          const unsigned short* __restrict__ Wp1,
          const float* __restrict__ b0p, const float* __restrict__ b1p,
          unsigned short* __restrict__ h1r, unsigned short* __restrict__ h2r,
          float* __restrict__ c2, unsigned int* __restrict__ cnt)
{
  __shared__ unsigned short w_lds[32768];   // 64KB: per-block W slice
  __shared__ float gl[2][64][36];           // 18KB: gate staging
  __shared__ float bias_sm[32];
  const int blk = blockIdx.x;
  if (blk < 64) scan_body<true >(blk, xe, Wp0, b0p, h1r, h2r, c2, cnt, w_lds, gl, bias_sm);
  else          scan_body<false>(blk, xe, Wp1, b1p, h1r, h2r, c2, cnt, w_lds, gl, bias_sm);
}

// ---------------- final projection: out = c2 @ Wout^T + bout ----------------
__global__ void outproj(const float* __restrict__ c2, const float* __restrict__ Wout,
                        const float* __restrict__ bout, float* __restrict__ out)
{
  int t = threadIdx.x;
  if (t >= 640) return;
  int b = t / 10, l = t % 10;
  float s = bout[l];
  #pragma unroll 8
  for (int h = 0; h < 512; ++h) s += c2[b * 512 + h] * Wout[l * 512 + h];
  out[b * 10 + l] = s;
}

extern "C" void kernel_launch(void* const* d_in, const int* in_sizes, int n_in,
                              void* d_out, int out_size, void* d_ws, size_t ws_size,
                              hipStream_t stream) {
  (void)in_sizes; (void)n_in; (void)out_size; (void)ws_size;
  const int*   x    = (const int*)  d_in[0];
  const float* emb  = (const float*)d_in[1];
  const float* Wih0 = (const float*)d_in[2];
  const float* Whh0 = (const float*)d_in[3];
  const float* bih0 = (const float*)d_in[4];
  const float* bhh0 = (const float*)d_in[5];
  const float* Wih1 = (const float*)d_in[6];
  const float* Whh1 = (const float*)d_in[7];
  const float* bih1 = (const float*)d_in[8];
  const float* bhh1 = (const float*)d_in[9];
  const float* Wout = (const float*)d_in[10];
  const float* bout = (const float*)d_in[11];
  float* out = (float*)d_out;

  char* ws = (char*)d_ws;
  unsigned int*   cnt = (unsigned int*)  (ws + OFF_ARR);
  unsigned short* h1r = (unsigned short*)(ws + OFF_H1);
  unsigned short* h2r = (unsigned short*)(ws + OFF_H2);
  float*          c2  = (float*)         (ws + OFF_C2);
  unsigned short* xe  = (unsigned short*)(ws + OFF_XE);
  unsigned short* Wp0 = (unsigned short*)(ws + OFF_W0);
  unsigned short* Wp1 = (unsigned short*)(ws + OFF_W1);
  float*          b0p = (float*)         (ws + OFF_B0);
  float*          b1p = (float*)         (ws + OFF_B1);

  hipMemsetAsync(ws, 0, MEMSET_BYTES, stream);   // counters + epoch + h rings = 0
  prep_weights<<<8192, 256, 0, stream>>>(Wih0, Whh0, bih0, bhh0, Wih1, Whh1, bih1, bhh1,
                                         Wp0, Wp1, b0p, b1p);
  gather_xe<<<40960, 256, 0, stream>>>(x, emb, xe);
  lstm_scan<<<128, 512, 0, stream>>>(xe, Wp0, Wp1, b0p, b1p, h1r, h2r, c2, cnt);
  outproj<<<1, 640, 0, stream>>>(c2, Wout, bout, out);
}

// Round 8
// 2239.658 us; speedup vs baseline: 1.0043x; 1.0043x over previous
//
#include <hip/hip_runtime.h>
#include <hip/hip_bf16.h>
#include <stdint.h>

// Problem dims
#define BB 64     // batch
#define SS 512    // seq len
#define HH 512    // hidden
#define DD 300    // embed dim
#define DP 320    // embed dim padded to K%32==0

typedef __attribute__((ext_vector_type(8))) short short8;  // 8 x bf16
typedef __attribute__((ext_vector_type(4))) float f32x4;

__device__ __forceinline__ unsigned short f2bf(float f) {
  unsigned u = __builtin_bit_cast(unsigned, f);
  u += 0x7fffu + ((u >> 16) & 1u);       // RNE
  return (unsigned short)(u >> 16);
}
__device__ __forceinline__ float sigm(float x) { return 1.f / (1.f + __expf(-x)); }
__device__ __forceinline__ float tanh_f(float x) {
  float t = __expf(-2.f * fabsf(x));
  float r = (1.f - t) / (1.f + t);
  return x < 0.f ? -r : r;
}

// Coalesced 16B loads (lane l reads base + l*16). sc1 -> agent-scope (MALL-coherent).
// Results are NOT valid until an explicit s_waitcnt vmcnt(0)!
__device__ __forceinline__ short8 load_frag_sc1(const unsigned short* p) {
  short8 r;
  asm volatile("global_load_dwordx4 %0, %1, off sc1" : "=v"(r) : "v"(p));
  return r;
}
__device__ __forceinline__ short8 load_frag(const unsigned short* p) {
  short8 r;
  asm volatile("global_load_dwordx4 %0, %1, off" : "=v"(r) : "v"(p));
  return r;
}

// ---------------- workspace layout (bytes) ----------------
// Frag-ready layouts: element (b, c) of a [64 x 32*NKB] bf16 panel lives at
// 2B-unit addr: (c>>5)*2048 + (b>>4)*512 + ((c>>3)&3)*128 + (b&15)*8 + (c&7)
// so MFMA A-frag (mtile m, kblk) = base + kblk*2048 + m*512 + lane*8, 16B/lane.
#define OFF_ARR   0u          // 16 arrival counters, 512B spaced -> 8192
#define OFF_EP    8192u       // (reserved)
#define OFF_H1    16384u      // h1 ring [2][64KB frag-layout] -> 131072
#define OFF_H2    147456u     // h2 ring [2][64KB frag-layout] -> 131072
#define OFF_C2    278528u     // c2 [64][512] f32 -> 131072
#define OFF_XE    409600u     // xe frag-layout [512][10 kblk][4KB] -> 20971520
#define OFF_W0    21381120u   // Wp0 [2048][832] bf16 -> 3407872
#define OFF_W1    24788992u   // Wp1 [2048][1024] bf16 -> 4194304
#define OFF_B0    28983296u   // bias0p [2048] f32
#define OFF_B1    28991488u   // bias1p [2048] f32
#define MEMSET_BYTES 278528u  // counters + reserved + both h rings

// ---------------- weight prep (row-major Wp, round-6 layout) ----------------
// Row reorder: grow = lblk*32 + l, gate = l>>3 (i,f,g,o), orig = gate*512 + lblk*8 + (l&7).
// Wp0 row: [ W_hh0 | W_ih0 | pad ] (A = [h1_prev | x_t]); Wp1 row: [ W_ih1 | W_hh1 ].
__global__ void prep_weights(const float* __restrict__ Wih0, const float* __restrict__ Whh0,
                             const float* __restrict__ bih0, const float* __restrict__ bhh0,
                             const float* __restrict__ Wih1, const float* __restrict__ Whh1,
                             const float* __restrict__ bih1, const float* __restrict__ bhh1,
                             unsigned short* __restrict__ Wp0, unsigned short* __restrict__ Wp1,
                             float* __restrict__ b0p, float* __restrict__ b1p)
{
  int idx = blockIdx.x * 256 + threadIdx.x;   // over 2048*1024
  int grow = idx >> 10;
  int k1 = idx & 1023;
  int l = grow & 31;
  int lb = grow >> 5;
  int gate = l >> 3;
  int orig = gate * 512 + lb * 8 + (l & 7);
  float v1 = (k1 < 512) ? Wih1[orig * 512 + k1] : Whh1[orig * 512 + (k1 - 512)];
  Wp1[idx] = f2bf(v1);
  if (k1 < 832) {
    float v0;
    if (k1 < 512)      v0 = Whh0[orig * 512 + k1];
    else if (k1 < 812) v0 = Wih0[orig * 300 + (k1 - 512)];
    else               v0 = 0.f;
    Wp0[grow * 832 + k1] = f2bf(v0);
  }
  if (k1 == 0) {
    b0p[grow] = bih0[orig] + bhh0[orig];
    b1p[grow] = bih1[orig] + bhh1[orig];
  }
}

// ---------------- embedding gather -> frag-ready layout ----------------
__global__ void gather_xe(const int* __restrict__ x, const float* __restrict__ emb,
                          unsigned short* __restrict__ xe)
{
  int idx = blockIdx.x * 256 + threadIdx.x;   // SS*BB*DP = 10485760
  int dk = idx % DP;
  int rem = idx / DP;
  int b = rem % BB;
  int t = rem / BB;
  int tok = x[b * SS + t];
  float v = (dk < DD) ? emb[(size_t)tok * DD + dk] : 0.f;
  size_t ua = (size_t)t * 20480 + (size_t)(dk >> 5) * 2048 + (size_t)(b >> 4) * 512
            + (size_t)((dk >> 3) & 3) * 128 + (size_t)(b & 15) * 8 + (dk & 7);
  xe[ua] = f2bf(v);
}

// ---------------- persistent pipelined 2-layer scan ----------------
// 128 blocks x 512 thr; blk<64 -> L0, else L1. Iter k: L0 step t=k (k<512),
// L1 step t=k-1 (k>=1). Barrier (round-8): 16 arrival counters (blk>>3,
// 8 contenders each); wave0 of EVERY block polls all 16 directly (lanes 0-15,
// one 64-lane load, __all, no sleep) -> 3 serialized hops/step
// (drain, add, detect) instead of round-6's 5 (master+epoch removed).
template<bool IS_L0>
__device__ __forceinline__ void scan_body(
    int blk,
    const unsigned short* __restrict__ xe,
    const unsigned short* __restrict__ Wp,
    const float* __restrict__ biasP,
    unsigned short* __restrict__ h1r,
    unsigned short* __restrict__ h2r,
    float* __restrict__ c2,
    unsigned int* cnt,
    float (&gl)[2][64][36], float (&bias_sm)[32])
{
  constexpr int K  = IS_L0 ? 832 : 1024;
  constexpr int NK = IS_L0 ? 13 : 16;      // kblks per khalf

  const int tid  = threadIdx.x;
  const int lane = tid & 63;
  const int wave = tid >> 6;
  const int lrow = lane & 15;
  const int m    = wave & 3;
  const int q    = wave >> 2;
  const int lblk = IS_L0 ? blk : blk - 64;
  const int qkb  = q * NK;                 // first global kblk of this wave

  if (tid < 32) bias_sm[tid] = biasP[lblk * 32 + tid];

  // Persistent W fragments (cached loads; compiler may rematerialize from
  // L1/L2 inside the loop -- measured cheap, see rounds 6/7).
  short8 Bf0[NK], Bf1[NK];
  {
    const unsigned short* wr0 = Wp + (size_t)(lblk * 32 + lrow) * K + qkb * 32 + (lane >> 4) * 8;
    const unsigned short* wr1 = wr0 + (size_t)16 * K;
    #pragma unroll
    for (int j = 0; j < NK; ++j) {
      Bf0[j] = *(const short8*)(wr0 + j * 32);
      Bf1[j] = *(const short8*)(wr1 + j * 32);
    }
  }
  #pragma unroll
  for (int j = 0; j < NK; ++j)
    asm volatile("" : "+v"(Bf0[j]), "+v"(Bf1[j]));

  float creg = 0.f;                 // cell state: 1 cell per thread
  const int pb = tid >> 3;          // pointwise batch
  const int ph = tid & 7;           // pointwise h-offset
  // pointwise h-store unit address (frag layout), constant part:
  const size_t hst = (size_t)(lblk >> 2) * 2048 + (size_t)(pb >> 4) * 512
                   + (size_t)(lblk & 3) * 128 + (size_t)(pb & 15) * 8 + ph;

  for (int k = 0;; ++k) {
    const bool active = IS_L0 ? (k < 512) : (k >= 1);
    short8 a[NK];

    // ---- prefetch cacheable xe fragments (L0 only) before the wait ----
    if (IS_L0 && active) {
      const unsigned short* xet = xe + (size_t)k * 20480;
      #pragma unroll
      for (int j = 0; j < NK; ++j) {
        const int kg = qkb + j;
        if (kg >= 16)
          a[j] = load_frag(xet + (size_t)(kg - 16) * 2048 + (size_t)m * 512 + lane * 8);
      }
    }

    // ---- barrier wait: wave0 polls all 16 counters directly, no sleep ----
    if (k >= 1) {
      if (wave == 0) {
        const unsigned tgt = (unsigned)k * 8u;
        int guard = 0;
        for (;;) {
          unsigned v = (lane < 16)
              ? __hip_atomic_load(cnt + lane * 128, __ATOMIC_RELAXED, __HIP_MEMORY_SCOPE_AGENT)
              : tgt;
          if (__all(v >= tgt)) break;
          if (++guard > (1 << 18)) break;   // liveness insurance
        }
      }
      __syncthreads();
    }

    if (active) {
      const int t = IS_L0 ? k : k - 1;
      const unsigned short* hA = h1r + (size_t)((IS_L0 ? (t + 1) : t) & 1) * 32768;
      const unsigned short* hB = h2r + (size_t)((t + 1) & 1) * 32768;

      // ---- h fragment loads (coalesced sc1, issued immediately post-barrier) ----
      #pragma unroll
      for (int j = 0; j < NK; ++j) {
        const int kg = qkb + j;
        if (kg < 16) {
          a[j] = load_frag_sc1(hA + (size_t)kg * 2048 + (size_t)m * 512 + lane * 8);
        } else if (!IS_L0) {
          a[j] = load_frag_sc1(hB + (size_t)(kg - 16) * 2048 + (size_t)m * 512 + lane * 8);
        }
      }
      asm volatile("s_waitcnt vmcnt(0)" ::: "memory");
      __builtin_amdgcn_sched_barrier(0);

      // ---- MFMA ----
      f32x4 acc0 = {0.f, 0.f, 0.f, 0.f};
      f32x4 acc1 = {0.f, 0.f, 0.f, 0.f};
      #pragma unroll
      for (int j = 0; j < NK; ++j) {
        acc0 = __builtin_amdgcn_mfma_f32_16x16x32_bf16(a[j], Bf0[j], acc0, 0, 0, 0);
        acc1 = __builtin_amdgcn_mfma_f32_16x16x32_bf16(a[j], Bf1[j], acc1, 0, 0, 0);
      }
      #pragma unroll
      for (int r = 0; r < 4; ++r) {
        const int bb = m * 16 + (lane >> 4) * 4 + r;
        gl[q][bb][lrow]      = acc0[r];
        gl[q][bb][16 + lrow] = acc1[r];
      }
      __syncthreads();

      // ---- pointwise gates + frag-layout h store (contiguous per wave) ----
      {
        float gi = gl[0][pb][ph]      + gl[1][pb][ph]      + bias_sm[ph];
        float gf = gl[0][pb][8 + ph]  + gl[1][pb][8 + ph]  + bias_sm[8 + ph];
        float gg = gl[0][pb][16 + ph] + gl[1][pb][16 + ph] + bias_sm[16 + ph];
        float go = gl[0][pb][24 + ph] + gl[1][pb][24 + ph] + bias_sm[24 + ph];
        float iv = sigm(gi), fv = sigm(gf), ov = sigm(go), gv = tanh_f(gg);
        creg = fv * creg + iv * gv;
        float hv = ov * tanh_f(creg);
        unsigned short hb = f2bf(hv);
        unsigned pair = (unsigned)hb | ((unsigned)(unsigned short)__shfl_down((int)hb, 1) << 16);
        unsigned short* hw = (IS_L0 ? h1r : h2r) + (size_t)(t & 1) * 32768 + hst;
        if ((ph & 1) == 0)
          __hip_atomic_store((unsigned*)hw, pair, __ATOMIC_RELAXED, __HIP_MEMORY_SCOPE_AGENT);
        if (!IS_L0 && k == 512) c2[pb * HH + lblk * 8 + ph] = creg;
      }
      // drain h stores to the coherence point before signaling
      asm volatile("s_waitcnt vmcnt(0)" ::: "memory");
    }

    if (k == 512) break;
    // ---- signal iteration-k completion (8 contenders per counter) ----
    __syncthreads();
    if (tid == 0)
      __hip_atomic_fetch_add(cnt + (blk >> 3) * 128, 1u, __ATOMIC_RELAXED,
                             __HIP_MEMORY_SCOPE_AGENT);
  }
}

__attribute__((amdgpu_waves_per_eu(2, 2)))
__global__ void __launch_bounds__(512)
lstm_scan(const unsigned short* __restrict__ xe,
          const unsigned short* __restrict__ Wp0,
          const unsigned short* __restrict__ Wp1,
          const float* __restrict__ b0p, const float* __restrict__ b1p,
          unsigned short* __restrict__ h1r, unsigned short* __restrict__ h2r,
          float* __restrict__ c2, unsigned int* __restrict__ cnt)
{
  __shared__ float gl[2][64][36];
  __shared__ float bias_sm[32];
  const int blk = blockIdx.x;
  if (blk < 64) scan_body<true >(blk, xe, Wp0, b0p, h1r, h2r, c2, cnt, gl, bias_sm);
  else          scan_body<false>(blk, xe, Wp1, b1p, h1r, h2r, c2, cnt, gl, bias_sm);
}

// ---------------- final projection: out = c2 @ Wout^T + bout ----------------
__global__ void outproj(const float* __restrict__ c2, const float* __restrict__ Wout,
                        const float* __restrict__ bout, float* __restrict__ out)
{
  int t = threadIdx.x;
  if (t >= 640) return;
  int b = t / 10, l = t % 10;
  float s = bout[l];
  #pragma unroll 8
  for (int h = 0; h < 512; ++h) s += c2[b * 512 + h] * Wout[l * 512 + h];
  out[b * 10 + l] = s;
}

extern "C" void kernel_launch(void* const* d_in, const int* in_sizes, int n_in,
                              void* d_out, int out_size, void* d_ws, size_t ws_size,
                              hipStream_t stream) {
  (void)in_sizes; (void)n_in; (void)out_size; (void)ws_size;
  const int*   x    = (const int*)  d_in[0];
  const float* emb  = (const float*)d_in[1];
  const float* Wih0 = (const float*)d_in[2];
  const float* Whh0 = (const float*)d_in[3];
  const float* bih0 = (const float*)d_in[4];
  const float* bhh0 = (const float*)d_in[5];
  const float* Wih1 = (const float*)d_in[6];
  const float* Whh1 = (const float*)d_in[7];
  const float* bih1 = (const float*)d_in[8];
  const float* bhh1 = (const float*)d_in[9];
  const float* Wout = (const float*)d_in[10];
  const float* bout = (const float*)d_in[11];
  float* out = (float*)d_out;

  char* ws = (char*)d_ws;
  unsigned int*   cnt = (unsigned int*)  (ws + OFF_ARR);
  unsigned short* h1r = (unsigned short*)(ws + OFF_H1);
  unsigned short* h2r = (unsigned short*)(ws + OFF_H2);
  float*          c2  = (float*)         (ws + OFF_C2);
  unsigned short* xe  = (unsigned short*)(ws + OFF_XE);
  unsigned short* Wp0 = (unsigned short*)(ws + OFF_W0);
  unsigned short* Wp1 = (unsigned short*)(ws + OFF_W1);
  float*          b0p = (float*)         (ws + OFF_B0);
  float*          b1p = (float*)         (ws + OFF_B1);

  hipMemsetAsync(ws, 0, MEMSET_BYTES, stream);   // counters + h rings = 0
  prep_weights<<<8192, 256, 0, stream>>>(Wih0, Whh0, bih0, bhh0, Wih1, Whh1, bih1, bhh1,
                                         Wp0, Wp1, b0p, b1p);
  gather_xe<<<40960, 256, 0, stream>>>(x, emb, xe);
  lstm_scan<<<128, 512, 0, stream>>>(xe, Wp0, Wp1, b0p, b1p, h1r, h2r, c2, cnt);
  outproj<<<1, 640, 0, stream>>>(c2, Wout, bout, out);
}

// Round 9
// 1916.371 us; speedup vs baseline: 1.1737x; 1.1687x over previous
//
#include <hip/hip_runtime.h>
#include <hip/hip_bf16.h>
#include <stdint.h>

// Problem dims
#define BB 64     // batch
#define SS 512    // seq len
#define HH 512    // hidden
#define DD 300    // embed dim
#define DP 320    // embed dim padded to K%32==0

typedef __attribute__((ext_vector_type(8))) short short8;  // 8 x bf16
typedef __attribute__((ext_vector_type(4))) float f32x4;

__device__ __forceinline__ unsigned short f2bf(float f) {
  unsigned u = __builtin_bit_cast(unsigned, f);
  u += 0x7fffu + ((u >> 16) & 1u);       // RNE
  return (unsigned short)(u >> 16);
}
__device__ __forceinline__ float sigm(float x) { return 1.f / (1.f + __expf(-x)); }
__device__ __forceinline__ float tanh_f(float x) {
  float t = __expf(-2.f * fabsf(x));
  float r = (1.f - t) / (1.f + t);
  return x < 0.f ? -r : r;
}

// Coalesced 16B loads (lane l reads base + l*16). sc1 -> agent-scope (MALL-coherent).
// Results NOT valid until an explicit s_waitcnt vmcnt(0)!
__device__ __forceinline__ short8 load_frag_sc1(const unsigned short* p) {
  short8 r;
  asm volatile("global_load_dwordx4 %0, %1, off sc1" : "=v"(r) : "v"(p));
  return r;
}
__device__ __forceinline__ short8 load_frag(const unsigned short* p) {
  short8 r;
  asm volatile("global_load_dwordx4 %0, %1, off" : "=v"(r) : "v"(p));
  return r;
}
__device__ __forceinline__ unsigned ld_seq(const unsigned int* p) {
  return __hip_atomic_load(p, __ATOMIC_RELAXED, __HIP_MEMORY_SCOPE_AGENT);
}
__device__ __forceinline__ void st_seq(unsigned int* p, unsigned v) {
  __hip_atomic_store(p, v, __ATOMIC_RELAXED, __HIP_MEMORY_SCOPE_AGENT);
}

// ---------------- workspace layout (bytes) ----------------
// Frag-ready layouts: element (b, c) of a [64 x 32*NKB] bf16 panel lives at
// 2B-unit addr: (c>>5)*2048 + (b>>4)*512 + ((c>>3)&3)*128 + (b&15)*8 + (c&7)
// so MFMA A-frag (mtile m, kblk) = base + kblk*2048 + m*512 + lane*8, 16B/lane.
// Sync: store-only seq words (NO atomics). h1seq[64] @0 (64B spaced),
// l1seq[64] @4096. seq[b] = number of steps block b has completed.
#define OFF_SEQ   0u          // 2 x 64 words x 64B -> 8192
#define OFF_H1    8192u       // h1 ring [4][64KB frag-layout] -> 262144
#define OFF_H2    270336u     // h2 ring [2][64KB frag-layout] -> 131072
#define OFF_C2    401408u     // c2 [64][512] f32 -> 131072
#define OFF_XE    532480u     // xe frag-layout [512][10 kblk][4KB] -> 20971520
#define OFF_W0    21504000u   // Wp0 [2048][832] bf16 -> 3407872
#define OFF_W1    24911872u   // Wp1 [2048][1024] bf16 -> 4194304
#define OFF_B0    29106176u   // bias0p [2048] f32
#define OFF_B1    29114368u   // bias1p [2048] f32
#define MEMSET_BYTES 401408u  // seqs + h1 ring + h2 ring

// ---------------- weight prep (row-major Wp, round-6 layout) ----------------
// Row reorder: grow = lblk*32 + l, gate = l>>3 (i,f,g,o), orig = gate*512 + lblk*8 + (l&7).
// Wp0 row: [ W_hh0 | W_ih0 | pad ] (A = [h1_prev | x_t]); Wp1 row: [ W_ih1 | W_hh1 ].
__global__ void prep_weights(const float* __restrict__ Wih0, const float* __restrict__ Whh0,
                             const float* __restrict__ bih0, const float* __restrict__ bhh0,
                             const float* __restrict__ Wih1, const float* __restrict__ Whh1,
                             const float* __restrict__ bih1, const float* __restrict__ bhh1,
                             unsigned short* __restrict__ Wp0, unsigned short* __restrict__ Wp1,
                             float* __restrict__ b0p, float* __restrict__ b1p)
{
  int idx = blockIdx.x * 256 + threadIdx.x;   // over 2048*1024
  int grow = idx >> 10;
  int k1 = idx & 1023;
  int l = grow & 31;
  int lb = grow >> 5;
  int gate = l >> 3;
  int orig = gate * 512 + lb * 8 + (l & 7);
  float v1 = (k1 < 512) ? Wih1[orig * 512 + k1] : Whh1[orig * 512 + (k1 - 512)];
  Wp1[idx] = f2bf(v1);
  if (k1 < 832) {
    float v0;
    if (k1 < 512)      v0 = Whh0[orig * 512 + k1];
    else if (k1 < 812) v0 = Wih0[orig * 300 + (k1 - 512)];
    else               v0 = 0.f;
    Wp0[grow * 832 + k1] = f2bf(v0);
  }
  if (k1 == 0) {
    b0p[grow] = bih0[orig] + bhh0[orig];
    b1p[grow] = bih1[orig] + bhh1[orig];
  }
}

// ---------------- embedding gather -> frag-ready layout ----------------
__global__ void gather_xe(const int* __restrict__ x, const float* __restrict__ emb,
                          unsigned short* __restrict__ xe)
{
  int idx = blockIdx.x * 256 + threadIdx.x;   // SS*BB*DP = 10485760
  int dk = idx % DP;
  int rem = idx / DP;
  int b = rem % BB;
  int t = rem / BB;
  int tok = x[b * SS + t];
  float v = (dk < DD) ? emb[(size_t)tok * DD + dk] : 0.f;
  size_t ua = (size_t)t * 20480 + (size_t)(dk >> 5) * 2048 + (size_t)(b >> 4) * 512
            + (size_t)((dk >> 3) & 3) * 128 + (size_t)(b & 15) * 8 + (dk & 7);
  xe[ua] = f2bf(v);
}

// ---------------- layer-0 persistent scan (64 blocks) ----------------
// Step t: reads h1(t-1) [slot (t+3)&3] + xe(t), writes h1(t) [slot t&3].
// Wait: all h1seq >= t (peers done t-1) AND all l1seq >= t-3 (ring-4 back-pressure).
__device__ __forceinline__ void scan_l0(
    int lblk,
    const unsigned short* __restrict__ xe,
    const unsigned short* __restrict__ Wp,
    const float* __restrict__ biasP,
    unsigned short* __restrict__ h1r,
    unsigned int* h1seq, unsigned int* l1seq,
    float (&gl)[2][64][36], float (&bias_sm)[32])
{
  constexpr int K = 832, NK = 13;
  const int tid  = threadIdx.x;
  const int lane = tid & 63;
  const int wave = tid >> 6;
  const int lrow = lane & 15;
  const int m    = wave & 3;
  const int q    = wave >> 2;
  const int qkb  = q * NK;

  if (tid < 32) bias_sm[tid] = biasP[lblk * 32 + tid];

  short8 Bf0[NK], Bf1[NK];
  {
    const unsigned short* wr0 = Wp + (size_t)(lblk * 32 + lrow) * K + qkb * 32 + (lane >> 4) * 8;
    const unsigned short* wr1 = wr0 + (size_t)16 * K;
    #pragma unroll
    for (int j = 0; j < NK; ++j) {
      Bf0[j] = *(const short8*)(wr0 + j * 32);
      Bf1[j] = *(const short8*)(wr1 + j * 32);
    }
  }
  #pragma unroll
  for (int j = 0; j < NK; ++j) asm volatile("" : "+v"(Bf0[j]), "+v"(Bf1[j]));

  float creg = 0.f;
  const int pb = tid >> 3;
  const int ph = tid & 7;
  const size_t hst = (size_t)(lblk >> 2) * 2048 + (size_t)(pb >> 4) * 512
                   + (size_t)(lblk & 3) * 128 + (size_t)(pb & 15) * 8 + ph;

  for (int t = 0; t < 512; ++t) {
    short8 a[NK];
    // xe prefetch (cached) before the wait
    {
      const unsigned short* xet = xe + (size_t)t * 20480;
      #pragma unroll
      for (int j = 0; j < NK; ++j) {
        const int kg = qkb + j;
        if (kg >= 16)
          a[j] = load_frag(xet + (size_t)(kg - 16) * 2048 + (size_t)m * 512 + lane * 8);
      }
    }
    if (t >= 1) {
      if (wave == 0) {
        int guard = 0;
        for (;;) {
          unsigned v1 = ld_seq(h1seq + lane * 16);
          unsigned v2 = ld_seq(l1seq + lane * 16);
          bool ok = (v1 >= (unsigned)t) && ((int)v2 >= t - 3);
          if (__all(ok)) break;
          if (++guard > (1 << 20)) break;   // liveness insurance
          __builtin_amdgcn_s_sleep(1);
        }
      }
      __syncthreads();
    }
    // h1(t-1) fragment loads (sc1, coalesced)
    {
      const unsigned short* hA = h1r + (size_t)((t + 3) & 3) * 32768;
      #pragma unroll
      for (int j = 0; j < NK; ++j) {
        const int kg = qkb + j;
        if (kg < 16)
          a[j] = load_frag_sc1(hA + (size_t)kg * 2048 + (size_t)m * 512 + lane * 8);
      }
    }
    asm volatile("s_waitcnt vmcnt(0)" ::: "memory");
    __builtin_amdgcn_sched_barrier(0);

    f32x4 acc0 = {0.f, 0.f, 0.f, 0.f};
    f32x4 acc1 = {0.f, 0.f, 0.f, 0.f};
    #pragma unroll
    for (int j = 0; j < NK; ++j) {
      acc0 = __builtin_amdgcn_mfma_f32_16x16x32_bf16(a[j], Bf0[j], acc0, 0, 0, 0);
      acc1 = __builtin_amdgcn_mfma_f32_16x16x32_bf16(a[j], Bf1[j], acc1, 0, 0, 0);
    }
    #pragma unroll
    for (int r = 0; r < 4; ++r) {
      const int bb = m * 16 + (lane >> 4) * 4 + r;
      gl[q][bb][lrow]      = acc0[r];
      gl[q][bb][16 + lrow] = acc1[r];
    }
    __syncthreads();
    {
      float gi = gl[0][pb][ph]      + gl[1][pb][ph]      + bias_sm[ph];
      float gf = gl[0][pb][8 + ph]  + gl[1][pb][8 + ph]  + bias_sm[8 + ph];
      float gg = gl[0][pb][16 + ph] + gl[1][pb][16 + ph] + bias_sm[16 + ph];
      float go = gl[0][pb][24 + ph] + gl[1][pb][24 + ph] + bias_sm[24 + ph];
      float iv = sigm(gi), fv = sigm(gf), ov = sigm(go), gv = tanh_f(gg);
      creg = fv * creg + iv * gv;
      float hv = ov * tanh_f(creg);
      unsigned short hb = f2bf(hv);
      unsigned pair = (unsigned)hb | ((unsigned)(unsigned short)__shfl_down((int)hb, 1) << 16);
      unsigned short* hw = h1r + (size_t)(t & 3) * 32768 + hst;
      if ((ph & 1) == 0)
        __hip_atomic_store((unsigned*)hw, pair, __ATOMIC_RELAXED, __HIP_MEMORY_SCOPE_AGENT);
    }
    asm volatile("s_waitcnt vmcnt(0)" ::: "memory");   // h visible before seq
    __syncthreads();
    if (tid == 0) st_seq(h1seq + lblk * 16, (unsigned)(t + 1));
  }
}

// ---------------- layer-1 persistent scan (64 blocks) ----------------
// Step t: reads h1(t) [slot t&3] + h2(t-1) [slot (t+1)&1], writes h2(t) [slot t&1].
// Dependency-split: q=0 half (h1 operand) starts after h1seq >= t+1 (slack);
// q=1 half (h2 operand, the recurrence) starts after l1seq >= t, polled by
// wave4 CONCURRENTLY with q=0's load+MFMA work.
__device__ __forceinline__ void scan_l1(
    int lblk,
    const unsigned short* __restrict__ Wp,
    const float* __restrict__ biasP,
    const unsigned short* __restrict__ h1r,
    unsigned short* __restrict__ h2r,
    float* __restrict__ c2,
    unsigned int* h1seq, unsigned int* l1seq,
    float (&gl)[2][64][36], float (&bias_sm)[32])
{
  constexpr int K = 1024, NK = 16;
  const int tid  = threadIdx.x;
  const int lane = tid & 63;
  const int wave = tid >> 6;
  const int lrow = lane & 15;
  const int m    = wave & 3;
  const int q    = wave >> 2;
  const int qkb  = q * NK;

  if (tid < 32) bias_sm[tid] = biasP[lblk * 32 + tid];

  short8 Bf0[NK], Bf1[NK];
  {
    const unsigned short* wr0 = Wp + (size_t)(lblk * 32 + lrow) * K + qkb * 32 + (lane >> 4) * 8;
    const unsigned short* wr1 = wr0 + (size_t)16 * K;
    #pragma unroll
    for (int j = 0; j < NK; ++j) {
      Bf0[j] = *(const short8*)(wr0 + j * 32);
      Bf1[j] = *(const short8*)(wr1 + j * 32);
    }
  }
  #pragma unroll
  for (int j = 0; j < NK; ++j) asm volatile("" : "+v"(Bf0[j]), "+v"(Bf1[j]));

  float creg = 0.f;
  const int pb = tid >> 3;
  const int ph = tid & 7;
  const size_t hst = (size_t)(lblk >> 2) * 2048 + (size_t)(pb >> 4) * 512
                   + (size_t)(lblk & 3) * 128 + (size_t)(pb & 15) * 8 + ph;

  for (int t = 0; t < 512; ++t) {
    // ---- phase A: wait for h1(t) (usually slack; L0 runs ahead) ----
    if (wave == 0) {
      int guard = 0;
      for (;;) {
        unsigned v = ld_seq(h1seq + lane * 16);
        if (__all(v >= (unsigned)(t + 1))) break;
        if (++guard > (1 << 20)) break;
        __builtin_amdgcn_s_sleep(1);
      }
    }
    __syncthreads();   // S1

    // ---- q=0: load h1 + MFMA + stage, WHILE wave4 polls the recurrence ----
    if (q == 0) {
      const unsigned short* hA = h1r + (size_t)(t & 3) * 32768;
      short8 a[NK];
      #pragma unroll
      for (int j = 0; j < NK; ++j)
        a[j] = load_frag_sc1(hA + (size_t)j * 2048 + (size_t)m * 512 + lane * 8);
      asm volatile("s_waitcnt vmcnt(0)" ::: "memory");
      __builtin_amdgcn_sched_barrier(0);
      f32x4 acc0 = {0.f, 0.f, 0.f, 0.f};
      f32x4 acc1 = {0.f, 0.f, 0.f, 0.f};
      #pragma unroll
      for (int j = 0; j < NK; ++j) {
        acc0 = __builtin_amdgcn_mfma_f32_16x16x32_bf16(a[j], Bf0[j], acc0, 0, 0, 0);
        acc1 = __builtin_amdgcn_mfma_f32_16x16x32_bf16(a[j], Bf1[j], acc1, 0, 0, 0);
      }
      #pragma unroll
      for (int r = 0; r < 4; ++r) {
        const int bb = m * 16 + (lane >> 4) * 4 + r;
        gl[0][bb][lrow]      = acc0[r];
        gl[0][bb][16 + lrow] = acc1[r];
      }
    } else if (wave == 4) {
      int guard = 0;
      for (;;) {
        unsigned v = ld_seq(l1seq + lane * 16);
        if (__all(v >= (unsigned)t)) break;
        if (++guard > (1 << 20)) break;
        __builtin_amdgcn_s_sleep(1);
      }
    }
    __syncthreads();   // S2: h2(t-1) ready everywhere

    if (q == 1) {
      const unsigned short* hB = h2r + (size_t)((t + 1) & 1) * 32768;
      short8 a[NK];
      #pragma unroll
      for (int j = 0; j < NK; ++j)
        a[j] = load_frag_sc1(hB + (size_t)j * 2048 + (size_t)m * 512 + lane * 8);
      asm volatile("s_waitcnt vmcnt(0)" ::: "memory");
      __builtin_amdgcn_sched_barrier(0);
      f32x4 acc0 = {0.f, 0.f, 0.f, 0.f};
      f32x4 acc1 = {0.f, 0.f, 0.f, 0.f};
      #pragma unroll
      for (int j = 0; j < NK; ++j) {
        acc0 = __builtin_amdgcn_mfma_f32_16x16x32_bf16(a[j], Bf0[j], acc0, 0, 0, 0);
        acc1 = __builtin_amdgcn_mfma_f32_16x16x32_bf16(a[j], Bf1[j], acc1, 0, 0, 0);
      }
      #pragma unroll
      for (int r = 0; r < 4; ++r) {
        const int bb = m * 16 + (lane >> 4) * 4 + r;
        gl[1][bb][lrow]      = acc0[r];
        gl[1][bb][16 + lrow] = acc1[r];
      }
    }
    __syncthreads();   // S3

    {
      float gi = gl[0][pb][ph]      + gl[1][pb][ph]      + bias_sm[ph];
      float gf = gl[0][pb][8 + ph]  + gl[1][pb][8 + ph]  + bias_sm[8 + ph];
      float gg = gl[0][pb][16 + ph] + gl[1][pb][16 + ph] + bias_sm[16 + ph];
      float go = gl[0][pb][24 + ph] + gl[1][pb][24 + ph] + bias_sm[24 + ph];
      float iv = sigm(gi), fv = sigm(gf), ov = sigm(go), gv = tanh_f(gg);
      creg = fv * creg + iv * gv;
      float hv = ov * tanh_f(creg);
      unsigned short hb = f2bf(hv);
      unsigned pair = (unsigned)hb | ((unsigned)(unsigned short)__shfl_down((int)hb, 1) << 16);
      unsigned short* hw = h2r + (size_t)(t & 1) * 32768 + hst;
      if ((ph & 1) == 0)
        __hip_atomic_store((unsigned*)hw, pair, __ATOMIC_RELAXED, __HIP_MEMORY_SCOPE_AGENT);
      if (t == 511) c2[pb * HH + lblk * 8 + ph] = creg;
    }
    asm volatile("s_waitcnt vmcnt(0)" ::: "memory");   // h2 visible before seq
    __syncthreads();   // S4
    if (tid == 0) st_seq(l1seq + lblk * 16, (unsigned)(t + 1));
  }
}

__attribute__((amdgpu_waves_per_eu(2, 2)))
__global__ void __launch_bounds__(512)
lstm_scan(const unsigned short* __restrict__ xe,
          const unsigned short* __restrict__ Wp0,
          const unsigned short* __restrict__ Wp1,
          const float* __restrict__ b0p, const float* __restrict__ b1p,
          unsigned short* __restrict__ h1r, unsigned short* __restrict__ h2r,
          float* __restrict__ c2, unsigned int* __restrict__ seqbase)
{
  __shared__ float gl[2][64][36];
  __shared__ float bias_sm[32];
  unsigned int* h1seq = seqbase;
  unsigned int* l1seq = seqbase + 1024;   // byte 4096
  const int blk = blockIdx.x;
  if (blk < 64) scan_l0(blk,      xe, Wp0, b0p, h1r, h1seq, l1seq, gl, bias_sm);
  else          scan_l1(blk - 64, Wp1, b1p, h1r, h2r, c2, h1seq, l1seq, gl, bias_sm);
}

// ---------------- final projection: out = c2 @ Wout^T + bout ----------------
__global__ void outproj(const float* __restrict__ c2, const float* __restrict__ Wout,
                        const float* __restrict__ bout, float* __restrict__ out)
{
  int t = threadIdx.x;
  if (t >= 640) return;
  int b = t / 10, l = t % 10;
  float s = bout[l];
  #pragma unroll 8
  for (int h = 0; h < 512; ++h) s += c2[b * 512 + h] * Wout[l * 512 + h];
  out[b * 10 + l] = s;
}

extern "C" void kernel_launch(void* const* d_in, const int* in_sizes, int n_in,
                              void* d_out, int out_size, void* d_ws, size_t ws_size,
                              hipStream_t stream) {
  (void)in_sizes; (void)n_in; (void)out_size; (void)ws_size;
  const int*   x    = (const int*)  d_in[0];
  const float* emb  = (const float*)d_in[1];
  const float* Wih0 = (const float*)d_in[2];
  const float* Whh0 = (const float*)d_in[3];
  const float* bih0 = (const float*)d_in[4];
  const float* bhh0 = (const float*)d_in[5];
  const float* Wih1 = (const float*)d_in[6];
  const float* Whh1 = (const float*)d_in[7];
  const float* bih1 = (const float*)d_in[8];
  const float* bhh1 = (const float*)d_in[9];
  const float* Wout = (const float*)d_in[10];
  const float* bout = (const float*)d_in[11];
  float* out = (float*)d_out;

  char* ws = (char*)d_ws;
  unsigned int*   seqb = (unsigned int*)  (ws + OFF_SEQ);
  unsigned short* h1r  = (unsigned short*)(ws + OFF_H1);
  unsigned short* h2r  = (unsigned short*)(ws + OFF_H2);
  float*          c2   = (float*)         (ws + OFF_C2);
  unsigned short* xe   = (unsigned short*)(ws + OFF_XE);
  unsigned short* Wp0  = (unsigned short*)(ws + OFF_W0);
  unsigned short* Wp1  = (unsigned short*)(ws + OFF_W1);
  float*          b0p  = (float*)         (ws + OFF_B0);
  float*          b1p  = (float*)         (ws + OFF_B1);

  hipMemsetAsync(ws, 0, MEMSET_BYTES, stream);   // seqs + h rings = 0
  prep_weights<<<8192, 256, 0, stream>>>(Wih0, Whh0, bih0, bhh0, Wih1, Whh1, bih1, bhh1,
                                         Wp0, Wp1, b0p, b1p);
  gather_xe<<<40960, 256, 0, stream>>>(x, emb, xe);
  lstm_scan<<<128, 512, 0, stream>>>(xe, Wp0, Wp1, b0p, b1p, h1r, h2r, c2, seqb);
  outproj<<<1, 640, 0, stream>>>(c2, Wout, bout, out);
}